// Round 8
// baseline (403.187 us; speedup 1.0000x reference)
//
#include <hip/hip_runtime.h>
#include <stdint.h>

typedef unsigned short u16;
typedef __attribute__((ext_vector_type(4))) float    floatx4;
typedef __attribute__((ext_vector_type(16))) float   floatx16;
typedef __attribute__((ext_vector_type(8))) __bf16   bf16x8;
typedef __attribute__((ext_vector_type(2))) unsigned int uintx2;
typedef __attribute__((ext_vector_type(4))) unsigned int uintx4;

__device__ inline u16 f2bf(float f) {            // RNE float->bf16
  unsigned int u = __builtin_bit_cast(unsigned int, f);
  u += 0x7fffu + ((u >> 16) & 1u);
  return (u16)(u >> 16);
}

#define GLD16(gsrc, ldst)                                                        \
  __builtin_amdgcn_global_load_lds(                                              \
      (__attribute__((address_space(1))) void*)(gsrc),                           \
      (__attribute__((address_space(3))) void*)(ldst), 16, 0, 0)

#define SB() __builtin_amdgcn_sched_barrier(0)

// ---------------------------------------------------------------------------
// combined prep: z<3 -> transpose-cast W_z into WT; z>=3 -> cast x -> bf16
__global__ __launch_bounds__(256) void prep_kernel(const float* __restrict__ x,
                                                   const float* __restrict__ Wq,
                                                   const float* __restrict__ Wk,
                                                   const float* __restrict__ Wv,
                                                   u16* __restrict__ xb,
                                                   u16* __restrict__ WT) {
  const int z = blockIdx.z;
  const int tid = threadIdx.y * 32 + threadIdx.x;
  if (z >= 3) {   // cast x chunk
    long blk = (long)(z - 3) * 1024 + blockIdx.y * 32 + blockIdx.x;
    long i = (blk * 256 + tid) * 8;
    floatx4 a = *(const floatx4*)(x + i);
    floatx4 b = *(const floatx4*)(x + i + 4);
    uintx4 o;
    o[0] = (unsigned)f2bf(a[0]) | ((unsigned)f2bf(a[1]) << 16);
    o[1] = (unsigned)f2bf(a[2]) | ((unsigned)f2bf(a[3]) << 16);
    o[2] = (unsigned)f2bf(b[0]) | ((unsigned)f2bf(b[1]) << 16);
    o[3] = (unsigned)f2bf(b[2]) | ((unsigned)f2bf(b[3]) << 16);
    *(uintx4*)(xb + i) = o;
    return;
  }
  __shared__ float tile[32][33];
  const float* W = (z == 0) ? Wq : (z == 1) ? Wk : Wv;
  u16* dst = WT + (long)z * 1024 * 1024;
  int bx = blockIdx.x * 32, by = blockIdx.y * 32;
  int tx = threadIdx.x, ty = threadIdx.y;                 // 32 x 8
  for (int i = 0; i < 32; i += 8)
    tile[ty + i][tx] = W[(long)(by + ty + i) * 1024 + bx + tx];
  __syncthreads();
  for (int i = 0; i < 32; i += 8)
    dst[(long)(bx + ty + i) * 1024 + by + tx] = f2bf(tile[tx][ty + i]);
}

// ---------------------------------------------------------------------------
// gemm_bt: C[m][n] = sum_k A[m][k] * Bt[n][k]   (A, Bt bf16, lda=ldb=K)
// 256x256 tile, BK=64, 512 threads = 8 waves (2M x 4N), per-wave 128x64.
// THIS ROUND: MFMA core switched to v_mfma_f32_32x32x16_bf16 (measured
// ceiling 2495 vs 2176 TF for 16x16, and HALF the instruction count ->
// frees SIMD issue slots for co-resident waves' ds_reads). Skeleton,
// staging, swizzle, vmcnt ledger are r4's verified ones (ledger re-sim'd:
// unchanged — ph0(t) needs B(t)+A0,A2(t), forced at ph3(t-1) vmcnt(2);
// ph1(t) needs A1,A3(t), forced at ph0(t) vmcnt(2)).
// Per-wave: 4(mi) x 2(ni) tiles of 32x32, K-tile = 4 ks-slices of 16.
// Fragment (swapped operands): lane reads row=base+(lane&31), k-chunk
// 2ks+(lane>>5); with the chunk swizzle slot=c^(r&7) this is
// addr = (row)*64 + ((half^l7)*8 ^ ks*16)  (XOR algebra, loop-invariant).
// C/D map (swapped): m = lane&31; n = (reg&3)+8*(reg>>2)+4*(lane>>5)
// -> 4 groups of 4 consecutive n-cols per acc tile (packed stores).
// Phases: ph0: ks0,1 x mi0,1 (+all B ks0,1, held in regs) | ph1: ks0,1 x
// mi2,3 | ph2: ks2,3 x mi0,1 (+B ks2,3) | ph3: ks2,3 x mi2,3.  8 MFMA each.
// Stage (t+1, opposite buf): ph0:B0,B1 ph1:B2,B3 ph2:A0,A2 ph3:A1,A3;
// vmcnt(2) at ph0 & ph3 (st1), vmcnt(0) at ph0 last tile.
// MODE 0: merged q|k projection; MODE 1: vT scatter; MODE 2: exp+rowsum;
// MODE 3: fp32 / lsum[row].
#define BM 256
#define BN 256
#define BK 64

template <int MODE, int GN>
__global__ __launch_bounds__(512, 2)
void gemm_bt(const u16* __restrict__ Aall, const u16* __restrict__ Ball,
             void* __restrict__ Call, void* __restrict__ C2,
             const float* __restrict__ bias, const float* __restrict__ bias2,
             float* __restrict__ lsum,
             int M, int N, int K, long aStride, long bStride, long cStride) {
  __shared__ __align__(16) u16 As[2][BM * BK];   // 2 x 32 KB
  __shared__ __align__(16) u16 Bs[2][BN * BK];   // 2 x 32 KB

  const int z = blockIdx.z;
  const u16* A  = Aall + (long)z * aStride;
  const u16* Bt = Ball + (long)z * bStride;

  // XCD-chunked bijective swizzle, then GN grouping
  int m_idx, n_idx;
  {
    const int tiles_n = gridDim.x, tiles_m = gridDim.y;
    int nwg = tiles_n * tiles_m;
    int bid = blockIdx.y * tiles_n + blockIdx.x;
    int qq = nwg >> 3;                       // all grids are %8 == 0
    int L = (bid & 7) * qq + (bid >> 3);
    int per_group = GN * tiles_m;
    int g = L / per_group;
    int rem = L - g * per_group;
    n_idx = g * GN + rem % GN;
    m_idx = rem / GN;
  }

  const int tid  = threadIdx.x;
  const int m0   = m_idx * BM;
  const int n0   = n_idx * BN;
  const int wave = tid >> 6;
  const int lane = tid & 63;
  const int wm   = (wave >> 2) * 128;    // wave row offset (2 waves in M)
  const int wn   = (wave & 3) * 64;      // wave col offset (4 waves in N)
  const int l31  = lane & 31;
  const int half = lane >> 5;
  const int l7   = lane & 7;

  floatx16 acc[4][2];
#pragma unroll
  for (int i = 0; i < 4; ++i)
#pragma unroll
    for (int j = 0; j < 2; ++j)
#pragma unroll
      for (int e = 0; e < 16; ++e) acc[i][j][e] = 0.f;

  // LDS fragment addressing (u16 units), loop-invariant:
  // addr(mi,ks) = (wrow + l31)*64 + mi*2048 + ((half^l7)*8 ^ (ks*16))
  const int swz  = (half ^ l7) * 8;
  const int aRow = (wm + l31) * 64;
  const int bRow = (wn + l31) * 64;
  int sx[4];
#pragma unroll
  for (int ks = 0; ks < 4; ++ks) sx[ks] = swz ^ (ks << 4);

  // staging (unchanged r4): unit u, chunk ci = u*512+tid -> row r=ci>>3,
  // slot sc=ci&7 holds source k-chunk sc^(r&7) (source-swizzle, rule #21).
  const u16* gA[4];
  const u16* gB[4];
#pragma unroll
  for (int i = 0; i < 4; ++i) {
    int ci = i * 512 + tid;
    int r = ci >> 3, sc = ci & 7;
    int col = (sc ^ (r & 7)) * 8;
    gA[i] = A  + (long)(m0 + r) * K + col;
    gB[i] = Bt + (long)(n0 + r) * K + col;
  }

  const int nt = K / BK;            // 16 or 32 here

  // prologue: all 8 units of tile 0, full drain, barrier (r4 verified)
  {
    u16* lA = (u16*)As + tid * 8;
    u16* lB = (u16*)Bs + tid * 8;
    GLD16(gB[0], lB);          GLD16(gB[1], lB + 4096);
    GLD16(gB[2], lB + 8192);   GLD16(gB[3], lB + 12288);
    GLD16(gA[0], lA);          GLD16(gA[1], lA + 4096);
    GLD16(gA[2], lA + 8192);   GLD16(gA[3], lA + 12288);
  }
  SB();
  asm volatile("s_waitcnt vmcnt(0)" ::: "memory");
  SB();
  __builtin_amdgcn_s_barrier();
  SB();
#pragma unroll
  for (int i = 0; i < 4; ++i) { gA[i] += BK; gB[i] += BK; }

  for (int t = 0; t < nt; ++t) {
    const int bo  = (t & 1) << 14;                   // buffer offset (u16)
    const u16* Ap = (const u16*)As + bo + aRow;
    const u16* Bp = (const u16*)Bs + bo + bRow;
    u16* ldsAn = (u16*)As + (bo ^ 16384) + tid * 8;  // next-buffer dests
    u16* ldsBn = (u16*)Bs + (bo ^ 16384) + tid * 8;
    const bool st1 = (t + 1 < nt);
    bf16x8 af[2][2], bfr[2][2];                      // [idx][ks-sub]

    // ========== phase 0: ks0,1 x mi0,1 ; load B ks0,1 (8 ds_reads) ======
#pragma unroll
    for (int mi = 0; mi < 2; ++mi)
#pragma unroll
      for (int ks = 0; ks < 2; ++ks)
        af[mi][ks] = *(const bf16x8*)(Ap + mi * 2048 + sx[ks]);
#pragma unroll
    for (int ni = 0; ni < 2; ++ni)
#pragma unroll
      for (int ks = 0; ks < 2; ++ks)
        bfr[ni][ks] = *(const bf16x8*)(Bp + ni * 2048 + sx[ks]);
    if (st1) { GLD16(gB[0], ldsBn); GLD16(gB[1], ldsBn + 4096); }
    SB();
    if (st1) asm volatile("s_waitcnt vmcnt(2)" ::: "memory"); // forces A1,A3(t)
    else     asm volatile("s_waitcnt vmcnt(0)" ::: "memory"); // final tile
    SB();
    __builtin_amdgcn_s_barrier();
    asm volatile("s_waitcnt lgkmcnt(0)" ::: "memory");
    SB();
    __builtin_amdgcn_s_setprio(1);
#pragma unroll
    for (int ks = 0; ks < 2; ++ks)
#pragma unroll
      for (int mi = 0; mi < 2; ++mi)
#pragma unroll
        for (int ni = 0; ni < 2; ++ni)
          acc[mi][ni] = __builtin_amdgcn_mfma_f32_32x32x16_bf16(
              bfr[ni][ks], af[mi][ks], acc[mi][ni], 0, 0, 0); // swapped
    __builtin_amdgcn_s_setprio(0);
    SB();

    // ========== phase 1: ks0,1 x mi2,3 (4 ds_reads; B held) =============
#pragma unroll
    for (int mi = 0; mi < 2; ++mi)
#pragma unroll
      for (int ks = 0; ks < 2; ++ks)
        af[mi][ks] = *(const bf16x8*)(Ap + (2 + mi) * 2048 + sx[ks]);
    if (st1) { GLD16(gB[2], ldsBn + 8192); GLD16(gB[3], ldsBn + 12288); }
    SB();
    __builtin_amdgcn_s_barrier();
    asm volatile("s_waitcnt lgkmcnt(0)" ::: "memory");
    SB();
    __builtin_amdgcn_s_setprio(1);
#pragma unroll
    for (int ks = 0; ks < 2; ++ks)
#pragma unroll
      for (int mi = 0; mi < 2; ++mi)
#pragma unroll
        for (int ni = 0; ni < 2; ++ni)
          acc[2 + mi][ni] = __builtin_amdgcn_mfma_f32_32x32x16_bf16(
              bfr[ni][ks], af[mi][ks], acc[2 + mi][ni], 0, 0, 0);
    __builtin_amdgcn_s_setprio(0);
    SB();

    // ========== phase 2: ks2,3 x mi0,1 ; load B ks2,3 (8 ds_reads) ======
#pragma unroll
    for (int mi = 0; mi < 2; ++mi)
#pragma unroll
      for (int ks = 0; ks < 2; ++ks)
        af[mi][ks] = *(const bf16x8*)(Ap + mi * 2048 + sx[2 + ks]);
#pragma unroll
    for (int ni = 0; ni < 2; ++ni)
#pragma unroll
      for (int ks = 0; ks < 2; ++ks)
        bfr[ni][ks] = *(const bf16x8*)(Bp + ni * 2048 + sx[2 + ks]);
    if (st1) { GLD16(gA[0], ldsAn); GLD16(gA[2], ldsAn + 8192); }
    SB();
    __builtin_amdgcn_s_barrier();
    asm volatile("s_waitcnt lgkmcnt(0)" ::: "memory");
    SB();
    __builtin_amdgcn_s_setprio(1);
#pragma unroll
    for (int ks = 0; ks < 2; ++ks)
#pragma unroll
      for (int mi = 0; mi < 2; ++mi)
#pragma unroll
        for (int ni = 0; ni < 2; ++ni)
          acc[mi][ni] = __builtin_amdgcn_mfma_f32_32x32x16_bf16(
              bfr[ni][ks], af[mi][ks], acc[mi][ni], 0, 0, 0);
    __builtin_amdgcn_s_setprio(0);
    SB();

    // ========== phase 3: ks2,3 x mi2,3 (4 ds_reads) =====================
#pragma unroll
    for (int mi = 0; mi < 2; ++mi)
#pragma unroll
      for (int ks = 0; ks < 2; ++ks)
        af[mi][ks] = *(const bf16x8*)(Ap + (2 + mi) * 2048 + sx[2 + ks]);
    if (st1) { GLD16(gA[1], ldsAn + 4096); GLD16(gA[3], ldsAn + 12288); }
    SB();
    if (st1) asm volatile("s_waitcnt vmcnt(2)" ::: "memory"); // B+A0,A2(t+1)
    SB();
    __builtin_amdgcn_s_barrier();
    asm volatile("s_waitcnt lgkmcnt(0)" ::: "memory");
    SB();
    __builtin_amdgcn_s_setprio(1);
#pragma unroll
    for (int ks = 0; ks < 2; ++ks)
#pragma unroll
      for (int mi = 0; mi < 2; ++mi)
#pragma unroll
        for (int ni = 0; ni < 2; ++ni)
          acc[2 + mi][ni] = __builtin_amdgcn_mfma_f32_32x32x16_bf16(
              bfr[ni][ks], af[mi][ks], acc[2 + mi][ni], 0, 0, 0);
    __builtin_amdgcn_s_setprio(0);
    SB();

#pragma unroll
    for (int i = 0; i < 4; ++i) { gA[i] += BK; gB[i] += BK; }
  }

  // epilogue (swapped 32x32 D layout): m = lane&31; per acc tile the 16 regs
  // = 4 groups (rg) of 4 consecutive n-cols at n = ni*32 + rg*8 + half*4.
#pragma unroll
  for (int mi = 0; mi < 4; ++mi) {
    const int row = m0 + wm + mi * 32 + l31;      // fixed per lane
    if (MODE == 2) {
      u16* C = (u16*)Call + (long)z * cStride;
      float rs = 0.f;
#pragma unroll
      for (int ni = 0; ni < 2; ++ni)
#pragma unroll
        for (int rg = 0; rg < 4; ++rg) {
          int colb = n0 + wn + ni * 32 + rg * 8 + half * 4;
          float e0 = __expf(acc[mi][ni][rg * 4 + 0] * 0.03125f);
          float e1 = __expf(acc[mi][ni][rg * 4 + 1] * 0.03125f);
          float e2 = __expf(acc[mi][ni][rg * 4 + 2] * 0.03125f);
          float e3 = __expf(acc[mi][ni][rg * 4 + 3] * 0.03125f);
          rs += (e0 + e1) + (e2 + e3);
          uintx2 o;
          o[0] = (unsigned)f2bf(e0) | ((unsigned)f2bf(e1) << 16);
          o[1] = (unsigned)f2bf(e2) | ((unsigned)f2bf(e3) << 16);
          *(uintx2*)(C + (long)row * N + colb) = o;
        }
      rs += __shfl_xor(rs, 32);                   // lanes l and l+32 share row
      if (half == 0) atomicAdd(lsum + (long)z * 2048 + row, rs);
    } else if (MODE == 3) {
      float* C = (float*)Call + (long)z * cStride;
      float inv = 1.0f / lsum[(long)z * 2048 + row];
#pragma unroll
      for (int ni = 0; ni < 2; ++ni)
#pragma unroll
        for (int rg = 0; rg < 4; ++rg) {
          int colb = n0 + wn + ni * 32 + rg * 8 + half * 4;
          floatx4 o = {acc[mi][ni][rg * 4 + 0] * inv,
                       acc[mi][ni][rg * 4 + 1] * inv,
                       acc[mi][ni][rg * 4 + 2] * inv,
                       acc[mi][ni][rg * 4 + 3] * inv};
          *(floatx4*)(C + (long)row * N + colb) = o;
        }
    } else if (MODE == 0) {
#pragma unroll
      for (int ni = 0; ni < 2; ++ni)
#pragma unroll
        for (int rg = 0; rg < 4; ++rg) {
          int colb = n0 + wn + ni * 32 + rg * 8 + half * 4;
          u16* C = (colb < 1024) ? (u16*)Call : (u16*)C2;
          const float* bp = (colb < 1024) ? bias + colb : bias2 + (colb - 1024);
          floatx4 b = *(const floatx4*)bp;
          uintx2 o;
          o[0] = (unsigned)f2bf(acc[mi][ni][rg * 4 + 0] + b[0]) |
                 ((unsigned)f2bf(acc[mi][ni][rg * 4 + 1] + b[1]) << 16);
          o[1] = (unsigned)f2bf(acc[mi][ni][rg * 4 + 2] + b[2]) |
                 ((unsigned)f2bf(acc[mi][ni][rg * 4 + 3] + b[3]) << 16);
          *(uintx2*)(C + (long)row * 1024 + (colb & 1023)) = o;
        }
    } else {  // MODE 1: vT scatter — row=do, cols=4 consecutive t
      u16* C = (u16*)Call;
      float b = bias[row];
#pragma unroll
      for (int ni = 0; ni < 2; ++ni)
#pragma unroll
        for (int rg = 0; rg < 4; ++rg) {
          int colb = n0 + wn + ni * 32 + rg * 8 + half * 4;  // global t index
          long base = ((long)(colb >> 11) * 1024) * 2048 + (colb & 2047);
          uintx2 o;
          o[0] = (unsigned)f2bf(acc[mi][ni][rg * 4 + 0] + b) |
                 ((unsigned)f2bf(acc[mi][ni][rg * 4 + 1] + b) << 16);
          o[1] = (unsigned)f2bf(acc[mi][ni][rg * 4 + 2] + b) |
                 ((unsigned)f2bf(acc[mi][ni][rg * 4 + 3] + b) << 16);
          *(uintx2*)(C + base + (long)row * 2048) = o;
        }
    }
  }
}

// ---------------------------------------------------------------------------
extern "C" void kernel_launch(void* const* d_in, const int* in_sizes, int n_in,
                              void* d_out, int out_size, void* d_ws, size_t ws_size,
                              hipStream_t stream) {
  const float* x  = (const float*)d_in[0];
  const float* Wq = (const float*)d_in[1];
  const float* bq = (const float*)d_in[2];
  const float* Wk = (const float*)d_in[3];
  const float* bk = (const float*)d_in[4];
  const float* Wv = (const float*)d_in[5];
  const float* bv = (const float*)d_in[6];
  float* out = (float*)d_out;

  const long BT = 16384;   // B*T
  u16* xb = (u16*)d_ws;                    // [16384,1024] bf16   32 MB
  u16* WT = xb + BT * 1024;                // [3][1024,1024]       6 MB
  u16* qb = WT + 3L * 1024 * 1024;         // [16384,1024]        32 MB
  u16* kb = qb + BT * 1024;                // [16384,1024]        32 MB
  u16* vT = kb + BT * 1024;                // [8][1024][2048]     32 MB
  u16* S  = vT + BT * 1024;                // [8][2048][2048]     64 MB
  float* lsum = (float*)(S + 8L * 2048 * 2048);   // [8][2048]    64 KB

  hipMemsetAsync(lsum, 0, 8 * 2048 * sizeof(float), stream);

  // z 0..2: transpose-cast W; z 3..10: cast x
  prep_kernel<<<dim3(32, 32, 11), dim3(32, 8), 0, stream>>>(x, Wq, Wk, Wv, xb, WT);

  // q|k = x [Wq|Wk] + [bq|bk]   (WT rows 0..2047 are Wq^T then Wk^T)
  gemm_bt<0, 8><<<dim3(8, 64, 1), 512, 0, stream>>>(
      xb, WT, qb, kb, bq, bk, nullptr, 16384, 2048, 1024, 0, 0, 0);
  // vT[b][do][t] = (Wv^T x^T + bv) : A=WvT [1024,1024], Bt=xb [16384,1024]
  gemm_bt<1, 8><<<dim3(64, 4, 1), 512, 0, stream>>>(
      WT + 2L * 1024 * 1024, xb, vT, nullptr, bv, nullptr, nullptr,
      1024, 16384, 1024, 0, 0, 0);
  // E[b] = exp(q_b k_b^T / 32), row-sums -> lsum
  gemm_bt<2, 8><<<dim3(8, 8, 8), 512, 0, stream>>>(
      qb, kb, S, nullptr, nullptr, nullptr, lsum,
      2048, 2048, 1024, 2048L * 1024, 2048L * 1024, 2048L * 2048);
  // out[b] = (E_b V_b) / lsum : A=E [2048,2048], Bt=vT_b [1024,2048]
  gemm_bt<3, 4><<<dim3(4, 8, 8), 512, 0, stream>>>(
      S, vT, out, nullptr, nullptr, nullptr, lsum,
      2048, 1024, 2048, 2048L * 2048, 1024L * 2048, 2048L * 1024);
}

// Round 9
// 372.603 us; speedup vs baseline: 1.0821x; 1.0821x over previous
//
#include <hip/hip_runtime.h>
#include <stdint.h>

typedef unsigned short u16;
typedef __attribute__((ext_vector_type(4))) float    floatx4;
typedef __attribute__((ext_vector_type(8))) __bf16   bf16x8;
typedef __attribute__((ext_vector_type(2))) unsigned int uintx2;
typedef __attribute__((ext_vector_type(4))) unsigned int uintx4;

__device__ inline u16 f2bf(float f) {            // RNE float->bf16
  unsigned int u = __builtin_bit_cast(unsigned int, f);
  u += 0x7fffu + ((u >> 16) & 1u);
  return (u16)(u >> 16);
}

#define GLD16(gsrc, ldst)                                                        \
  __builtin_amdgcn_global_load_lds(                                              \
      (__attribute__((address_space(1))) void*)(gsrc),                           \
      (__attribute__((address_space(3))) void*)(ldst), 16, 0, 0)

#define SB() __builtin_amdgcn_sched_barrier(0)

// ---------------------------------------------------------------------------
// combined prep: z<3 -> transpose-cast W_z into WT; z>=3 -> cast x -> bf16
__global__ __launch_bounds__(256) void prep_kernel(const float* __restrict__ x,
                                                   const float* __restrict__ Wq,
                                                   const float* __restrict__ Wk,
                                                   const float* __restrict__ Wv,
                                                   u16* __restrict__ xb,
                                                   u16* __restrict__ WT) {
  const int z = blockIdx.z;
  const int tid = threadIdx.y * 32 + threadIdx.x;
  if (z >= 3) {   // cast x chunk
    long blk = (long)(z - 3) * 1024 + blockIdx.y * 32 + blockIdx.x;
    long i = (blk * 256 + tid) * 8;
    floatx4 a = *(const floatx4*)(x + i);
    floatx4 b = *(const floatx4*)(x + i + 4);
    uintx4 o;
    o[0] = (unsigned)f2bf(a[0]) | ((unsigned)f2bf(a[1]) << 16);
    o[1] = (unsigned)f2bf(a[2]) | ((unsigned)f2bf(a[3]) << 16);
    o[2] = (unsigned)f2bf(b[0]) | ((unsigned)f2bf(b[1]) << 16);
    o[3] = (unsigned)f2bf(b[2]) | ((unsigned)f2bf(b[3]) << 16);
    *(uintx4*)(xb + i) = o;
    return;
  }
  __shared__ float tile[32][33];
  const float* W = (z == 0) ? Wq : (z == 1) ? Wk : Wv;
  u16* dst = WT + (long)z * 1024 * 1024;
  int bx = blockIdx.x * 32, by = blockIdx.y * 32;
  int tx = threadIdx.x, ty = threadIdx.y;                 // 32 x 8
  for (int i = 0; i < 32; i += 8)
    tile[ty + i][tx] = W[(long)(by + ty + i) * 1024 + bx + tx];
  __syncthreads();
  for (int i = 0; i < 32; i += 8)
    dst[(long)(bx + ty + i) * 1024 + by + tx] = f2bf(tile[tx][ty + i]);
}

// ---------------------------------------------------------------------------
// gemm_bt: C[m][n] = sum_k A[m][k] * Bt[n][k]   (A, Bt bf16, lda=ldb=K)
// WAVES/SIMD ROUND: 256x256 tile, BK=64, 1024 threads = 16 waves (4M x 4N),
// per-wave 64x64 (acc[4][4], 64 AGPR) -> 4 waves/SIMD at 1 block/CU
// (launch_bounds(1024,4) caps VGPR at 128). Per-CU per-K-tile MFMA/DMA
// identical to the 512-thread config; LDS reads 256 vs 192 b128 (still
// far under the MFMA floor). The ONLY changed axis vs r4 is waves/SIMD
// 2 -> 4 — m114's co-resident-wave stall-filling needs phase-diverse waves.
// MFMA core: 16x16x32 (r8's 32x32 had a forced 4-way read conflict).
// Schedule = r1's verified 2-phase, exact vmcnt ledger:
//   prologue: stage t0 (4 GLD16/thread-group units), stage t1; vmcnt(4)
//             [t0 landed, t1 in flight]; barrier.
//   iter t:  read ks0 frags; lgkm(0); MFMA ks0 x16;
//            read ks1 frags; lgkm(0); BARRIER (all waves' reads of buf[cur]
//            done -> safe overwrite); stage(t+2 -> buf[cur]) if t+2<nt;
//            MFMA ks1 x16; wait: t<=nt-3 -> vmcnt(4) [forces t+1, leaves
//            t+2]; t==nt-2 -> vmcnt(0) [forces t+1]; t==nt-1 -> none;
//            BARRIER [t+1 visible to all].
// Addressing/swizzle identical to r4 (0 conflicts verified): slot =
// chunk ^ (row&7), read col = ((quad ^ (l15&7))*8) ^ (ks*32 u16).
// MODE 0: merged q|k projection; MODE 1: vT scatter; MODE 2: exp+rowsum;
// MODE 3: fp32 / lsum[row].
#define BM 256
#define BN 256
#define BK 64

template <int MODE, int GN>
__global__ __launch_bounds__(1024, 4)
void gemm_bt(const u16* __restrict__ Aall, const u16* __restrict__ Ball,
             void* __restrict__ Call, void* __restrict__ C2,
             const float* __restrict__ bias, const float* __restrict__ bias2,
             float* __restrict__ lsum,
             int M, int N, int K, long aStride, long bStride, long cStride) {
  __shared__ __align__(16) u16 As[2][BM * BK];   // 2 x 32 KB
  __shared__ __align__(16) u16 Bs[2][BN * BK];   // 2 x 32 KB

  const int z = blockIdx.z;
  const u16* A  = Aall + (long)z * aStride;
  const u16* Bt = Ball + (long)z * bStride;

  // XCD-chunked bijective swizzle, then GN grouping
  int m_idx, n_idx;
  {
    const int tiles_n = gridDim.x, tiles_m = gridDim.y;
    int nwg = tiles_n * tiles_m;
    int bid = blockIdx.y * tiles_n + blockIdx.x;
    int qq = nwg >> 3;                       // all grids are %8 == 0
    int L = (bid & 7) * qq + (bid >> 3);
    int per_group = GN * tiles_m;
    int g = L / per_group;
    int rem = L - g * per_group;
    n_idx = g * GN + rem % GN;
    m_idx = rem / GN;
  }

  const int tid  = threadIdx.x;
  const int m0   = m_idx * BM;
  const int n0   = n_idx * BN;
  const int wave = tid >> 6;             // 0..15
  const int lane = tid & 63;
  const int wm   = (wave >> 2) * 64;     // wave row offset (4 waves in M)
  const int wn   = (wave & 3) * 64;      // wave col offset (4 waves in N)
  const int l15  = lane & 15;
  const int quad = lane >> 4;

  floatx4 acc[4][4];
  floatx4 zero = {0.f, 0.f, 0.f, 0.f};
#pragma unroll
  for (int i = 0; i < 4; ++i)
#pragma unroll
    for (int j = 0; j < 4; ++j) acc[i][j] = zero;

  // LDS read offsets (u16), loop-invariant. slot = (ks*4+quad)^(r&7),
  // r&7 == l15&7 (wm,wn,mi*16 all 0 mod 8); ks1 = ks0 ^ 32 (u16).
  const int swz   = (quad ^ (l15 & 7)) * 8;
  const int aOff0 = (wm + l15) * 64 + swz;
  const int bOff0 = (wn + l15) * 64 + swz;

  // staging: unit u in {A0,A1,B0,B1}; chunk ci = u*1024+tid -> row r=ci>>3
  // (128 rows/unit), slot sc=ci&7 holds source k-chunk sc^(r&7)
  // (source-swizzle, rule #21; identical algebra to r4).
  const u16* gA[2];
  const u16* gB[2];
#pragma unroll
  for (int i = 0; i < 2; ++i) {
    int ci = i * 1024 + tid;
    int r = ci >> 3, sc = ci & 7;
    int col = (sc ^ (r & 7)) * 8;
    gA[i] = A  + (long)(m0 + r) * K + col;
    gB[i] = Bt + (long)(n0 + r) * K + col;
  }

  const int nt = K / BK;            // 16 or 32 here

  // prologue: stage tile 0 -> buf0, tile 1 -> buf1; force tile 0; barrier.
  {
    u16* lA = (u16*)As + tid * 8;
    u16* lB = (u16*)Bs + tid * 8;
    GLD16(gA[0], lA); GLD16(gA[1], lA + 8192);
    GLD16(gB[0], lB); GLD16(gB[1], lB + 8192);
    GLD16(gA[0] + BK, lA + 16384); GLD16(gA[1] + BK, lA + 24576);
    GLD16(gB[0] + BK, lB + 16384); GLD16(gB[1] + BK, lB + 24576);
  }
  SB();
  asm volatile("s_waitcnt vmcnt(4)" ::: "memory");   // tile 0 landed
  SB();
  __builtin_amdgcn_s_barrier();
  SB();
#pragma unroll
  for (int i = 0; i < 2; ++i) { gA[i] += 2 * BK; gB[i] += 2 * BK; }

  for (int t = 0; t < nt; ++t) {
    const int bo  = (t & 1) << 14;                   // cur * 16384 u16 (32 KB)
    const u16* aP0 = (const u16*)As + bo + aOff0;          // ks0 base
    const u16* bP0 = (const u16*)Bs + bo + bOff0;
    const u16* aP1 = (const u16*)As + bo + (aOff0 ^ 32);   // ks1 base
    const u16* bP1 = (const u16*)Bs + bo + (bOff0 ^ 32);
    u16* ldsA = (u16*)As + bo + tid * 8;             // cur-buffer dests (t+2)
    u16* ldsB = (u16*)Bs + bo + tid * 8;
    bf16x8 af[4], bfr[4];

    // ---- phase ks0: 8 ds_reads, 16 MFMA ----
#pragma unroll
    for (int mi = 0; mi < 4; ++mi)
      af[mi] = *(const bf16x8*)(aP0 + mi * 1024);
#pragma unroll
    for (int ni = 0; ni < 4; ++ni)
      bfr[ni] = *(const bf16x8*)(bP0 + ni * 1024);
    asm volatile("s_waitcnt lgkmcnt(0)" ::: "memory");
    SB();
    __builtin_amdgcn_s_setprio(1);
#pragma unroll
    for (int mi = 0; mi < 4; ++mi)
#pragma unroll
      for (int ni = 0; ni < 4; ++ni)
        acc[mi][ni] = __builtin_amdgcn_mfma_f32_16x16x32_bf16(
            bfr[ni], af[mi], acc[mi][ni], 0, 0, 0);   // swapped operands
    __builtin_amdgcn_s_setprio(0);
    SB();

    // ---- phase ks1: 8 ds_reads, barrier, stage t+2 into cur, 16 MFMA ----
#pragma unroll
    for (int mi = 0; mi < 4; ++mi)
      af[mi] = *(const bf16x8*)(aP1 + mi * 1024);
#pragma unroll
    for (int ni = 0; ni < 4; ++ni)
      bfr[ni] = *(const bf16x8*)(bP1 + ni * 1024);
    asm volatile("s_waitcnt lgkmcnt(0)" ::: "memory");
    SB();
    __builtin_amdgcn_s_barrier();   // all waves done reading buf[cur]
    SB();
    if (t + 2 < nt) {
      GLD16(gA[0], ldsA); GLD16(gA[1], ldsA + 8192);
      GLD16(gB[0], ldsB); GLD16(gB[1], ldsB + 8192);
#pragma unroll
      for (int i = 0; i < 2; ++i) { gA[i] += BK; gB[i] += BK; }
    }
    SB();
    __builtin_amdgcn_s_setprio(1);
#pragma unroll
    for (int mi = 0; mi < 4; ++mi)
#pragma unroll
      for (int ni = 0; ni < 4; ++ni)
        acc[mi][ni] = __builtin_amdgcn_mfma_f32_16x16x32_bf16(
            bfr[ni], af[mi], acc[mi][ni], 0, 0, 0);
    __builtin_amdgcn_s_setprio(0);
    SB();
    // force tile t+1 before the barrier that opens iteration t+1
    if (t + 3 <= nt - 1)      asm volatile("s_waitcnt vmcnt(4)" ::: "memory");
    else if (t + 2 == nt - 1) asm volatile("s_waitcnt vmcnt(4)" ::: "memory");
    else if (t + 1 == nt - 1) asm volatile("s_waitcnt vmcnt(0)" ::: "memory");
    SB();
    __builtin_amdgcn_s_barrier();
    SB();
  }

  // epilogue (swapped D layout): row(m) = l15-based, 4 regs = 4 consecutive n-cols
#pragma unroll
  for (int mi = 0; mi < 4; ++mi) {
    const int row = m0 + wm + mi * 16 + l15;      // fixed per lane
    if (MODE == 2) {
      u16* C = (u16*)Call + (long)z * cStride;
      float rs = 0.f;
#pragma unroll
      for (int ni = 0; ni < 4; ++ni) {
        int colb = n0 + wn + ni * 16 + quad * 4;
        floatx4 v = acc[mi][ni];
        float e0 = __expf(v[0] * 0.03125f), e1 = __expf(v[1] * 0.03125f);
        float e2 = __expf(v[2] * 0.03125f), e3 = __expf(v[3] * 0.03125f);
        rs += (e0 + e1) + (e2 + e3);
        uintx2 o;
        o[0] = (unsigned)f2bf(e0) | ((unsigned)f2bf(e1) << 16);
        o[1] = (unsigned)f2bf(e2) | ((unsigned)f2bf(e3) << 16);
        *(uintx2*)(C + (long)row * N + colb) = o;
      }
      rs += __shfl_xor(rs, 16);
      rs += __shfl_xor(rs, 32);
      if (quad == 0) atomicAdd(lsum + (long)z * 2048 + row, rs);
    } else if (MODE == 3) {
      float* C = (float*)Call + (long)z * cStride;
      float inv = 1.0f / lsum[(long)z * 2048 + row];
#pragma unroll
      for (int ni = 0; ni < 4; ++ni) {
        int colb = n0 + wn + ni * 16 + quad * 4;
        floatx4 v = acc[mi][ni];
        floatx4 o = {v[0] * inv, v[1] * inv, v[2] * inv, v[3] * inv};
        *(floatx4*)(C + (long)row * N + colb) = o;
      }
    } else if (MODE == 0) {
#pragma unroll
      for (int ni = 0; ni < 4; ++ni) {
        int colb = n0 + wn + ni * 16 + quad * 4;
        u16* C = (colb < 1024) ? (u16*)Call : (u16*)C2;
        const float* bp = (colb < 1024) ? bias + colb : bias2 + (colb - 1024);
        floatx4 b = *(const floatx4*)bp;
        floatx4 v = acc[mi][ni];
        uintx2 o;
        o[0] = (unsigned)f2bf(v[0] + b[0]) | ((unsigned)f2bf(v[1] + b[1]) << 16);
        o[1] = (unsigned)f2bf(v[2] + b[2]) | ((unsigned)f2bf(v[3] + b[3]) << 16);
        *(uintx2*)(C + (long)row * 1024 + (colb & 1023)) = o;
      }
    } else {  // MODE 1: vT scatter — row=do, cols=4 consecutive t
      u16* C = (u16*)Call;
      float b = bias[row];
#pragma unroll
      for (int ni = 0; ni < 4; ++ni) {
        int colb = n0 + wn + ni * 16 + quad * 4;   // global t index over B*T
        long base = ((long)(colb >> 11) * 1024) * 2048 + (colb & 2047);
        floatx4 v = acc[mi][ni];
        uintx2 o;
        o[0] = (unsigned)f2bf(v[0] + b) | ((unsigned)f2bf(v[1] + b) << 16);
        o[1] = (unsigned)f2bf(v[2] + b) | ((unsigned)f2bf(v[3] + b) << 16);
        *(uintx2*)(C + base + (long)row * 2048) = o;
      }
    }
  }
}

// ---------------------------------------------------------------------------
extern "C" void kernel_launch(void* const* d_in, const int* in_sizes, int n_in,
                              void* d_out, int out_size, void* d_ws, size_t ws_size,
                              hipStream_t stream) {
  const float* x  = (const float*)d_in[0];
  const float* Wq = (const float*)d_in[1];
  const float* bq = (const float*)d_in[2];
  const float* Wk = (const float*)d_in[3];
  const float* bk = (const float*)d_in[4];
  const float* Wv = (const float*)d_in[5];
  const float* bv = (const float*)d_in[6];
  float* out = (float*)d_out;

  const long BT = 16384;   // B*T
  u16* xb = (u16*)d_ws;                    // [16384,1024] bf16   32 MB
  u16* WT = xb + BT * 1024;                // [3][1024,1024]       6 MB
  u16* qb = WT + 3L * 1024 * 1024;         // [16384,1024]        32 MB
  u16* kb = qb + BT * 1024;                // [16384,1024]        32 MB
  u16* vT = kb + BT * 1024;                // [8][1024][2048]     32 MB
  u16* S  = vT + BT * 1024;                // [8][2048][2048]     64 MB
  float* lsum = (float*)(S + 8L * 2048 * 2048);   // [8][2048]    64 KB

  hipMemsetAsync(lsum, 0, 8 * 2048 * sizeof(float), stream);

  // z 0..2: transpose-cast W; z 3..10: cast x
  prep_kernel<<<dim3(32, 32, 11), dim3(32, 8), 0, stream>>>(x, Wq, Wk, Wv, xb, WT);

  // q|k = x [Wq|Wk] + [bq|bk]   (WT rows 0..2047 are Wq^T then Wk^T)
  gemm_bt<0, 8><<<dim3(8, 64, 1), 1024, 0, stream>>>(
      xb, WT, qb, kb, bq, bk, nullptr, 16384, 2048, 1024, 0, 0, 0);
  // vT[b][do][t] = (Wv^T x^T + bv) : A=WvT [1024,1024], Bt=xb [16384,1024]
  gemm_bt<1, 8><<<dim3(64, 4, 1), 1024, 0, stream>>>(
      WT + 2L * 1024 * 1024, xb, vT, nullptr, bv, nullptr, nullptr,
      1024, 16384, 1024, 0, 0, 0);
  // E[b] = exp(q_b k_b^T / 32), row-sums -> lsum
  gemm_bt<2, 8><<<dim3(8, 8, 8), 1024, 0, stream>>>(
      qb, kb, S, nullptr, nullptr, nullptr, lsum,
      2048, 2048, 1024, 2048L * 1024, 2048L * 1024, 2048L * 2048);
  // out[b] = (E_b V_b) / lsum : A=E [2048,2048], Bt=vT_b [1024,2048]
  gemm_bt<3, 4><<<dim3(4, 8, 8), 1024, 0, stream>>>(
      S, vT, out, nullptr, nullptr, nullptr, lsum,
      2048, 1024, 2048, 2048L * 2048, 1024L * 2048, 2048L * 1024);
}